// Round 8
// baseline (429.530 us; speedup 1.0000x reference)
//
#include <hip/hip_runtime.h>
#include <hip/hip_bf16.h>

// Problem constants
#define VOCAB 10000
#define HID 256
#define BATCH 32
#define STEPS 256
#define MROWS (STEPS * BATCH)   // 8192

typedef __bf16 bf16x8 __attribute__((ext_vector_type(8)));
typedef float f32x4 __attribute__((ext_vector_type(4)));

// DPP quad_perm add (exact, direction-free within the quad).
template <int CTRL>
static __device__ __forceinline__ float dpp_add(float s) {
    int t = __builtin_amdgcn_update_dpp(
        0, __builtin_bit_cast(int, s), CTRL, 0xf, 0xf, true);
    return s + __builtin_bit_cast(float, t);
}
#define DPP_XOR1 0xB1   // quad_perm [1,0,3,2]
#define DPP_XOR2 0x4E   // quad_perm [2,3,0,1]

// Exact lane^4 exchange via ds_swizzle BitMode (xor=4, and=0x1F):
// offset = (4<<10) | 0x1F = 0x101F. Direction-free (round-7 bug: DPP
// row_ror:4 moves data to HIGHER lanes -> lane 0 got the neighboring
// 8-group's quad sum).
static __device__ __forceinline__ float swz4_add(float s) {
    int t = __builtin_amdgcn_ds_swizzle(__builtin_bit_cast(int, s), 0x101F);
    return s + __builtin_bit_cast(float, t);
}

// ---------------------------------------------------------------------------
// Kernel 1: transpose + convert W_d [256][10000] f32 -> WdT [10000][256] bf16
// ---------------------------------------------------------------------------
__global__ void transpose_wd_kernel(const float* __restrict__ Wd,
                                    __hip_bfloat16* __restrict__ WdT) {
    __shared__ __hip_bfloat16 tile[64][68];
    const int n0 = blockIdx.x * 64;
    const int k0 = blockIdx.y * 64;
    const int tid = threadIdx.x;
    const int lane = tid & 63;
    const int w = tid >> 6;

#pragma unroll
    for (int i = 0; i < 16; ++i) {
        int k = w * 16 + i;
        int n = lane;
        float v = (n0 + n < VOCAB) ? Wd[(size_t)(k0 + k) * VOCAB + n0 + n] : 0.f;
        tile[n][k] = __float2bfloat16(v);
    }
    __syncthreads();
#pragma unroll
    for (int i = 0; i < 16; ++i) {
        int n = w * 16 + i;
        int k = lane;
        if (n0 + n < VOCAB)
            WdT[(size_t)(n0 + n) * HID + k0 + k] = tile[n][k];
    }
}

// ---------------------------------------------------------------------------
// Kernel 2: gather + RNN recurrence — FULL F32 state (f16 state failed
// accuracy in round 6). 32 blocks x 1024 threads. Thread (cg = tid>>3,
// q = tid&7) computes cols {2cg, 2cg+1} over k in [q*32, q*32+32):
//   - w0[32]+w1[32] f32 = 64 VGPRs; 1024-thread block caps VGPR at 128;
//     in-loop empty-asm pins make w[] loop-carried (no sink/remat).
//   - h f32 in LDS, double-buffered; segment stride 36 floats -> the 8
//     broadcast addresses land on 8 disjoint 4-bank groups.
//   - 8-lane k-reduce: DPP xor1 + xor2 (quad-exact) + ds_swizzle xor4
//     (exact, direction-free). ALL lanes get the full sum.
//   - One barrier per step.
// ---------------------------------------------------------------------------
#define HSEG 36   // 32 + 4 pad: segment base bank = 4*q (all distinct)

__global__ __launch_bounds__(1024)
__attribute__((amdgpu_waves_per_eu(4, 4)))
void rnn_kernel(const int* __restrict__ tokens, const float* __restrict__ Wxh,
                const float* __restrict__ Whh, const float* __restrict__ bh,
                const float* __restrict__ h0, __hip_bfloat16* __restrict__ ybf,
                float* __restrict__ state_out) {
    const int b = blockIdx.x;
    const int tid = threadIdx.x;
    const int cg = tid >> 3;          // col-pair group 0..127
    const int q = tid & 7;            // k-eighth
    const int c0 = cg * 2;

    __shared__ alignas(16) float hseg[2][8][HSEG];

    // This thread's W_hh slice: w0[i] = Whh[q*32+i][c0], w1 = col c0+1.
    float w0[32], w1[32];
    {
        const float* wp = Whh + (size_t)(q * 32) * HID + c0;
#pragma unroll
        for (int i = 0; i < 32; ++i) {
            w0[i] = wp[(size_t)i * HID];
            w1[i] = wp[(size_t)i * HID + 1];
        }
    }

    const float bj0 = bh[c0];
    const float bj1 = bh[c0 + 1];
    const int* trow = tokens + b * STEPS;

    if (q == 0) {
        hseg[0][c0 >> 5][c0 & 31] = h0[b * HID + c0];
        hseg[0][c0 >> 5][(c0 & 31) + 1] = h0[b * HID + c0 + 1];
    }

    float2 xv = *reinterpret_cast<const float2*>(&Wxh[(size_t)trow[0] * HID + c0]);
    __syncthreads();

    float hn0 = 0.f, hn1 = 0.f;
    int cur = 0;
    for (int t = 0; t < STEPS; ++t) {
        // Keep the weight slice loop-carried (forbid remat/sink into loop).
#pragma unroll
        for (int i = 0; i < 32; ++i) {
            asm volatile("" : "+v"(w0[i]), "+v"(w1[i]));
        }

        // Prefetch next step's gathered x (hidden under the dot).
        int ti = (t + 1 < STEPS) ? t + 1 : STEPS - 1;
        float2 xn = *reinterpret_cast<const float2*>(
            &Wxh[(size_t)trow[ti] * HID + c0]);

        // Partial dot over this thread's 32 k-values (8 x float4 reads).
        const float* hb = &hseg[cur][q][0];
        float s0 = 0.f, s1 = 0.f;
#pragma unroll
        for (int j4 = 0; j4 < 8; ++j4) {
            float4 hv = *reinterpret_cast<const float4*>(&hb[j4 * 4]);
            s0 += hv.x * w0[j4 * 4 + 0] + hv.y * w0[j4 * 4 + 1] +
                  hv.z * w0[j4 * 4 + 2] + hv.w * w0[j4 * 4 + 3];
            s1 += hv.x * w1[j4 * 4 + 0] + hv.y * w1[j4 * 4 + 1] +
                  hv.z * w1[j4 * 4 + 2] + hv.w * w1[j4 * 4 + 3];
        }
        // Exact 8-lane reduce across the k-eighths.
        s0 = dpp_add<DPP_XOR1>(s0);  s1 = dpp_add<DPP_XOR1>(s1);
        s0 = dpp_add<DPP_XOR2>(s0);  s1 = dpp_add<DPP_XOR2>(s1);
        s0 = swz4_add(s0);           s1 = swz4_add(s1);

        // tanh(z) = 1 - 2/(exp(2z)+1)
        float z0 = xv.x + bj0 + s0;
        float z1 = xv.y + bj1 + s1;
        float e0 = __expf(2.f * z0);
        float e1 = __expf(2.f * z1);
        hn0 = 1.f - 2.f / (e0 + 1.f);
        hn1 = 1.f - 2.f / (e1 + 1.f);

        if (q == 0) {
            float2 hp = make_float2(hn0, hn1);
            *reinterpret_cast<float2*>(&hseg[cur ^ 1][c0 >> 5][c0 & 31]) = hp;
        } else if (q == 1) {
            __hip_bfloat162 yp;
            yp.x = __float2bfloat16(hn0);
            yp.y = __float2bfloat16(hn1);
            *reinterpret_cast<__hip_bfloat162*>(
                &ybf[(size_t)t * (BATCH * HID) + b * HID + c0]) = yp;
        }

        __syncthreads();
        cur ^= 1;
        xv = xn;
    }
    if (q == 1) {
        state_out[b * HID + c0] = hn0;
        state_out[b * HID + c0 + 1] = hn1;
    }
}

// ---------------------------------------------------------------------------
// Kernel 3: C[8192][10000] = Y_bf16 @ Wd^T_bf16 + b_d, f32 out.
// K=256 staged in LDS once (no k-loop barriers); B streamed from L2 with
// 1-deep prefetch. Swapped-operand MFMA: lane's 4 acc regs = 4 consecutive
// vocab cols -> f32x4 stores. (Validated: round-6 Output 0 passed.)
// ---------------------------------------------------------------------------
__global__ __launch_bounds__(256)
void gemm_kernel(const __hip_bfloat16* __restrict__ A,   // [8192][256]
                 const __hip_bfloat16* __restrict__ BT,  // [10000][256]
                 const float* __restrict__ bd,
                 float* __restrict__ C) {
    const int m0 = blockIdx.x * 128;
    const int n0 = blockIdx.y * 128;
    const int tid = threadIdx.x;
    const int lane = tid & 63;
    const int wv = tid >> 6;
    const int wr = wv >> 1;
    const int wc = wv & 1;
    const int r15 = lane & 15;
    const int g = lane >> 4;

    __shared__ alignas(16) __hip_bfloat16 As[128][264];

#pragma unroll
    for (int c = 0; c < 16; ++c) {
        int chunk = c * 256 + tid;
        int row = chunk >> 5;
        int cc = chunk & 31;
        bf16x8 av = *reinterpret_cast<const bf16x8*>(
            &A[(size_t)(m0 + row) * HID + cc * 8]);
        *reinterpret_cast<bf16x8*>(&As[row][cc * 8]) = av;
    }
    __syncthreads();

    const __hip_bfloat16* brow[4];
    bool bok[4];
#pragma unroll
    for (int n = 0; n < 4; ++n) {
        int rn = n0 + wc * 64 + n * 16 + r15;
        bok[n] = rn < VOCAB;
        brow[n] = BT + (size_t)(bok[n] ? rn : 0) * HID;
    }
    bf16x8 bzero;
#pragma unroll
    for (int e = 0; e < 8; ++e) bzero[e] = (__bf16)0.f;

    f32x4 acc[4][4] = {};
    bf16x8 bcur[4];
#pragma unroll
    for (int n = 0; n < 4; ++n)
        bcur[n] = bok[n] ? *reinterpret_cast<const bf16x8*>(&brow[n][g * 8])
                         : bzero;

    for (int kk8 = 0; kk8 < 8; ++kk8) {
        bf16x8 bnext[4];
        if (kk8 < 7) {
            int off = (kk8 + 1) * 32 + g * 8;
#pragma unroll
            for (int n = 0; n < 4; ++n)
                bnext[n] = bok[n]
                    ? *reinterpret_cast<const bf16x8*>(&brow[n][off])
                    : bzero;
        }
        bf16x8 af[4];
#pragma unroll
        for (int m = 0; m < 4; ++m)
            af[m] = *reinterpret_cast<const bf16x8*>(
                &As[wr * 64 + m * 16 + r15][kk8 * 32 + g * 8]);
#pragma unroll
        for (int m = 0; m < 4; ++m)
#pragma unroll
            for (int n = 0; n < 4; ++n)
                acc[m][n] = __builtin_amdgcn_mfma_f32_16x16x32_bf16(
                    bcur[n], af[m], acc[m][n], 0, 0, 0);
        if (kk8 < 7) {
#pragma unroll
            for (int n = 0; n < 4; ++n) bcur[n] = bnext[n];
        }
    }

    // Epilogue: element (reg r, lane) = C[m*16 + r15][n*16 + g*4 + r].
#pragma unroll
    for (int m = 0; m < 4; ++m) {
        int row = m0 + wr * 64 + m * 16 + r15;
#pragma unroll
        for (int n = 0; n < 4; ++n) {
            int cb = n0 + wc * 64 + n * 16;
            if (cb + 15 < VOCAB) {               // VOCAB%16==0 -> all-or-nothing
                int col = cb + g * 4;
                float4 bv = *reinterpret_cast<const float4*>(&bd[col]);
                f32x4 v = acc[m][n];
                v[0] += bv.x; v[1] += bv.y; v[2] += bv.z; v[3] += bv.w;
                *reinterpret_cast<f32x4*>(&C[(size_t)row * VOCAB + col]) = v;
            }
        }
    }
}

// ---------------------------------------------------------------------------
extern "C" void kernel_launch(void* const* d_in, const int* in_sizes, int n_in,
                              void* d_out, int out_size, void* d_ws, size_t ws_size,
                              hipStream_t stream) {
    const int* tokens  = (const int*)d_in[0];
    const float* Wxh   = (const float*)d_in[1];
    const float* Whh   = (const float*)d_in[2];
    const float* bh    = (const float*)d_in[3];
    const float* Wd    = (const float*)d_in[4];
    const float* bd    = (const float*)d_in[5];
    const float* h0    = (const float*)d_in[6];

    float* out = (float*)d_out;
    float* state_out = out + (size_t)MROWS * VOCAB;

    __hip_bfloat16* ybf = (__hip_bfloat16*)d_ws;
    __hip_bfloat16* wdt = (__hip_bfloat16*)((char*)d_ws + (size_t)MROWS * HID * 2);

    hipLaunchKernelGGL(transpose_wd_kernel, dim3(157, 4), dim3(256), 0, stream,
                       Wd, wdt);
    hipLaunchKernelGGL(rnn_kernel, dim3(BATCH), dim3(1024), 0, stream,
                       tokens, Wxh, Whh, bh, h0, ybf, state_out);
    hipLaunchKernelGGL(gemm_kernel, dim3(64, 79), dim3(256), 0, stream,
                       ybf, wdt, bd, out);
}

// Round 9
// 423.092 us; speedup vs baseline: 1.0152x; 1.0152x over previous
//
#include <hip/hip_runtime.h>
#include <hip/hip_bf16.h>

// Problem constants
#define VOCAB 10000
#define HID 256
#define BATCH 32
#define STEPS 256
#define MROWS (STEPS * BATCH)   // 8192

typedef __bf16 bf16x8 __attribute__((ext_vector_type(8)));
typedef float f32x4 __attribute__((ext_vector_type(4)));
typedef unsigned short u16x4 __attribute__((ext_vector_type(4)));

// DPP quad_perm add (exact, direction-free within the quad).
template <int CTRL>
static __device__ __forceinline__ float dpp_add(float s) {
    int t = __builtin_amdgcn_update_dpp(
        0, __builtin_bit_cast(int, s), CTRL, 0xf, 0xf, true);
    return s + __builtin_bit_cast(float, t);
}
#define DPP_XOR1 0xB1   // quad_perm [1,0,3,2]
#define DPP_XOR2 0x4E   // quad_perm [2,3,0,1]

// Exact lane^4 exchange via ds_swizzle BitMode (xor=4, and=0x1F).
static __device__ __forceinline__ float swz4_add(float s) {
    int t = __builtin_amdgcn_ds_swizzle(__builtin_bit_cast(int, s), 0x101F);
    return s + __builtin_bit_cast(float, t);
}

// ---------------------------------------------------------------------------
// Kernel 1: transpose + convert W_d [256][10000] f32 -> WdT [10000][256] bf16
// ---------------------------------------------------------------------------
__global__ void transpose_wd_kernel(const float* __restrict__ Wd,
                                    __hip_bfloat16* __restrict__ WdT) {
    __shared__ __hip_bfloat16 tile[64][68];
    const int n0 = blockIdx.x * 64;
    const int k0 = blockIdx.y * 64;
    const int tid = threadIdx.x;
    const int lane = tid & 63;
    const int w = tid >> 6;

#pragma unroll
    for (int i = 0; i < 16; ++i) {
        int k = w * 16 + i;
        int n = lane;
        float v = (n0 + n < VOCAB) ? Wd[(size_t)(k0 + k) * VOCAB + n0 + n] : 0.f;
        tile[n][k] = __float2bfloat16(v);
    }
    __syncthreads();
#pragma unroll
    for (int i = 0; i < 16; ++i) {
        int n = w * 16 + i;
        int k = lane;
        if (n0 + n < VOCAB)
            WdT[(size_t)(n0 + n) * HID + k0 + k] = tile[n][k];
    }
}

// ---------------------------------------------------------------------------
// Kernel 1b: transpose W_hh [256][256] f32 -> WhhT [256][256] f32 so each
// rnn thread's 32-k weight slice is CONTIGUOUS (dwordx4 loads whether the
// compiler keeps them resident or re-streams them from L2).
// ---------------------------------------------------------------------------
__global__ void transpose_whh_kernel(const float* __restrict__ Whh,
                                     float* __restrict__ WhhT) {
    __shared__ float tile[64][65];
    const int j0 = blockIdx.x * 64;
    const int k0 = blockIdx.y * 64;
    const int tid = threadIdx.x;
    const int lane = tid & 63;
    const int w = tid >> 6;

#pragma unroll
    for (int i = 0; i < 16; ++i) {
        int k = w * 16 + i;
        tile[lane][k] = Whh[(size_t)(k0 + k) * HID + j0 + lane];
    }
    __syncthreads();
#pragma unroll
    for (int i = 0; i < 16; ++i) {
        int j = w * 16 + i;
        WhhT[(size_t)(j0 + j) * HID + k0 + lane] = tile[j][lane];
    }
}

// ---------------------------------------------------------------------------
// Kernel 2: gather + RNN recurrence, f32 state (validated round 8).
// Round-8 post-mortem: asm pins forced AGPR ping-pong (~128 extra VALU
// instrs/thread/step, per-CU VALUBusy ~74%) -- pins REMOVED. Robust design:
// 32 blocks x 512 threads; thread (cg = tid>>3, q = tid&7) computes 4 cols
// {4cg..4cg+3} over k in [q*32, q*32+32):
//   - 4 cols share each h-read: LDS wave-instrs/step/CU 128 -> 64.
//   - weights w[4][32] from WhhT (contiguous): resident OR vector-streamed
//     from the 256-KB L2-resident buffer -- both acceptable.
//   - exact 8-lane reduce: DPP xor1 + xor2 + ds_swizzle xor4 (round-8 ok).
//   - h segments stride 36 floats (144 B = 16B-aligned, base banks 4q).
//   - one barrier per step.
// ---------------------------------------------------------------------------
#define HSEG 36

__global__ __launch_bounds__(512, 2)
__attribute__((amdgpu_waves_per_eu(2, 2)))
void rnn_kernel(const int* __restrict__ tokens, const float* __restrict__ Wxh,
                const float* __restrict__ WhhT, const float* __restrict__ bh,
                const float* __restrict__ h0, __hip_bfloat16* __restrict__ ybf,
                float* __restrict__ state_out) {
    const int b = blockIdx.x;
    const int tid = threadIdx.x;
    const int cg = tid >> 3;          // col-quad group 0..63
    const int q = tid & 7;            // k-eighth
    const int c0 = cg * 4;

    __shared__ alignas(16) float hseg[2][8][HSEG];

    // w[c][i] = WhhT[c0+c][q*32+i] -- contiguous 128 B per column.
    float w[4][32];
#pragma unroll
    for (int c = 0; c < 4; ++c) {
        const float4* wp = reinterpret_cast<const float4*>(
            WhhT + (size_t)(c0 + c) * HID + q * 32);
#pragma unroll
        for (int i4 = 0; i4 < 8; ++i4) {
            float4 v = wp[i4];
            w[c][i4 * 4 + 0] = v.x;
            w[c][i4 * 4 + 1] = v.y;
            w[c][i4 * 4 + 2] = v.z;
            w[c][i4 * 4 + 3] = v.w;
        }
    }

    const float4 bj = *reinterpret_cast<const float4*>(&bh[c0]);
    const int* trow = tokens + b * STEPS;

    if (q == 0) {
        *reinterpret_cast<float4*>(&hseg[0][c0 >> 5][c0 & 31]) =
            *reinterpret_cast<const float4*>(&h0[b * HID + c0]);
    }

    float4 xv = *reinterpret_cast<const float4*>(&Wxh[(size_t)trow[0] * HID + c0]);
    __syncthreads();

    float hn[4] = {0.f, 0.f, 0.f, 0.f};
    int cur = 0;
    for (int t = 0; t < STEPS; ++t) {
        // Prefetch next step's gathered x (hidden under the dot).
        int ti = (t + 1 < STEPS) ? t + 1 : STEPS - 1;
        float4 xn = *reinterpret_cast<const float4*>(
            &Wxh[(size_t)trow[ti] * HID + c0]);

        // Partial dots: 8 x float4 broadcast reads serve all 4 columns.
        const float* hb = &hseg[cur][q][0];
        float s[4] = {0.f, 0.f, 0.f, 0.f};
#pragma unroll
        for (int j4 = 0; j4 < 8; ++j4) {
            float4 hv = *reinterpret_cast<const float4*>(&hb[j4 * 4]);
#pragma unroll
            for (int c = 0; c < 4; ++c)
                s[c] += hv.x * w[c][j4 * 4 + 0] + hv.y * w[c][j4 * 4 + 1] +
                        hv.z * w[c][j4 * 4 + 2] + hv.w * w[c][j4 * 4 + 3];
        }
        // Exact 8-lane reduce across the k-eighths.
#pragma unroll
        for (int c = 0; c < 4; ++c) {
            s[c] = dpp_add<DPP_XOR1>(s[c]);
            s[c] = dpp_add<DPP_XOR2>(s[c]);
            s[c] = swz4_add(s[c]);
        }

        const float x4[4] = {xv.x, xv.y, xv.z, xv.w};
        const float b4[4] = {bj.x, bj.y, bj.z, bj.w};
#pragma unroll
        for (int c = 0; c < 4; ++c) {
            // tanh(z) = 1 - 2/(exp(2z)+1)
            float z = x4[c] + b4[c] + s[c];
            float e = __expf(2.f * z);
            hn[c] = 1.f - 2.f / (e + 1.f);
        }

        if (q == 0) {
            *reinterpret_cast<float4*>(&hseg[cur ^ 1][c0 >> 5][c0 & 31]) =
                make_float4(hn[0], hn[1], hn[2], hn[3]);
        } else if (q == 1) {
            u16x4 yv;
#pragma unroll
            for (int c = 0; c < 4; ++c)
                yv[c] = __builtin_bit_cast(unsigned short,
                                           __float2bfloat16(hn[c]));
            *reinterpret_cast<u16x4*>(
                &ybf[(size_t)t * (BATCH * HID) + b * HID + c0]) = yv;
        }

        __syncthreads();
        cur ^= 1;
        xv = xn;
    }
    if (q == 2) {
        *reinterpret_cast<float4*>(&state_out[b * HID + c0]) =
            make_float4(hn[0], hn[1], hn[2], hn[3]);
    }
}

// ---------------------------------------------------------------------------
// Kernel 3: C[8192][10000] = Y_bf16 @ Wd^T_bf16 + b_d, f32 out. (unchanged)
// ---------------------------------------------------------------------------
__global__ __launch_bounds__(256)
void gemm_kernel(const __hip_bfloat16* __restrict__ A,   // [8192][256]
                 const __hip_bfloat16* __restrict__ BT,  // [10000][256]
                 const float* __restrict__ bd,
                 float* __restrict__ C) {
    const int m0 = blockIdx.x * 128;
    const int n0 = blockIdx.y * 128;
    const int tid = threadIdx.x;
    const int lane = tid & 63;
    const int wv = tid >> 6;
    const int wr = wv >> 1;
    const int wc = wv & 1;
    const int r15 = lane & 15;
    const int g = lane >> 4;

    __shared__ alignas(16) __hip_bfloat16 As[128][264];

#pragma unroll
    for (int c = 0; c < 16; ++c) {
        int chunk = c * 256 + tid;
        int row = chunk >> 5;
        int cc = chunk & 31;
        bf16x8 av = *reinterpret_cast<const bf16x8*>(
            &A[(size_t)(m0 + row) * HID + cc * 8]);
        *reinterpret_cast<bf16x8*>(&As[row][cc * 8]) = av;
    }
    __syncthreads();

    const __hip_bfloat16* brow[4];
    bool bok[4];
#pragma unroll
    for (int n = 0; n < 4; ++n) {
        int rn = n0 + wc * 64 + n * 16 + r15;
        bok[n] = rn < VOCAB;
        brow[n] = BT + (size_t)(bok[n] ? rn : 0) * HID;
    }
    bf16x8 bzero;
#pragma unroll
    for (int e = 0; e < 8; ++e) bzero[e] = (__bf16)0.f;

    f32x4 acc[4][4] = {};
    bf16x8 bcur[4];
#pragma unroll
    for (int n = 0; n < 4; ++n)
        bcur[n] = bok[n] ? *reinterpret_cast<const bf16x8*>(&brow[n][g * 8])
                         : bzero;

    for (int kk8 = 0; kk8 < 8; ++kk8) {
        bf16x8 bnext[4];
        if (kk8 < 7) {
            int off = (kk8 + 1) * 32 + g * 8;
#pragma unroll
            for (int n = 0; n < 4; ++n)
                bnext[n] = bok[n]
                    ? *reinterpret_cast<const bf16x8*>(&brow[n][off])
                    : bzero;
        }
        bf16x8 af[4];
#pragma unroll
        for (int m = 0; m < 4; ++m)
            af[m] = *reinterpret_cast<const bf16x8*>(
                &As[wr * 64 + m * 16 + r15][kk8 * 32 + g * 8]);
#pragma unroll
        for (int m = 0; m < 4; ++m)
#pragma unroll
            for (int n = 0; n < 4; ++n)
                acc[m][n] = __builtin_amdgcn_mfma_f32_16x16x32_bf16(
                    bcur[n], af[m], acc[m][n], 0, 0, 0);
        if (kk8 < 7) {
#pragma unroll
            for (int n = 0; n < 4; ++n) bcur[n] = bnext[n];
        }
    }

    // Epilogue: element (reg r, lane) = C[m*16 + r15][n*16 + g*4 + r].
#pragma unroll
    for (int m = 0; m < 4; ++m) {
        int row = m0 + wr * 64 + m * 16 + r15;
#pragma unroll
        for (int n = 0; n < 4; ++n) {
            int cb = n0 + wc * 64 + n * 16;
            if (cb + 15 < VOCAB) {               // VOCAB%16==0 -> all-or-nothing
                int col = cb + g * 4;
                float4 bv = *reinterpret_cast<const float4*>(&bd[col]);
                f32x4 v = acc[m][n];
                v[0] += bv.x; v[1] += bv.y; v[2] += bv.z; v[3] += bv.w;
                *reinterpret_cast<f32x4*>(&C[(size_t)row * VOCAB + col]) = v;
            }
        }
    }
}

// ---------------------------------------------------------------------------
extern "C" void kernel_launch(void* const* d_in, const int* in_sizes, int n_in,
                              void* d_out, int out_size, void* d_ws, size_t ws_size,
                              hipStream_t stream) {
    const int* tokens  = (const int*)d_in[0];
    const float* Wxh   = (const float*)d_in[1];
    const float* Whh   = (const float*)d_in[2];
    const float* bh    = (const float*)d_in[3];
    const float* Wd    = (const float*)d_in[4];
    const float* bd    = (const float*)d_in[5];
    const float* h0    = (const float*)d_in[6];

    float* out = (float*)d_out;
    float* state_out = out + (size_t)MROWS * VOCAB;

    // Workspace: ybf bf16 [8192][256] (4 MB) | wdt bf16 [10000][256] (5 MB)
    //            | whhT f32 [256][256] (256 KB)
    char* wsb = (char*)d_ws;
    __hip_bfloat16* ybf = (__hip_bfloat16*)wsb;
    __hip_bfloat16* wdt = (__hip_bfloat16*)(wsb + (size_t)MROWS * HID * 2);
    float* whhT = (float*)(wsb + (size_t)MROWS * HID * 2 + (size_t)VOCAB * HID * 2);

    hipLaunchKernelGGL(transpose_whh_kernel, dim3(4, 4), dim3(256), 0, stream,
                       Whh, whhT);
    hipLaunchKernelGGL(transpose_wd_kernel, dim3(157, 4), dim3(256), 0, stream,
                       Wd, wdt);
    hipLaunchKernelGGL(rnn_kernel, dim3(BATCH), dim3(512), 0, stream,
                       tokens, Wxh, whhT, bh, h0, ybf, state_out);
    hipLaunchKernelGGL(gemm_kernel, dim3(64, 79), dim3(256), 0, stream,
                       ybf, wdt, bd, out);
}